// Round 2
// baseline (500.763 us; speedup 1.0000x reference)
//
#include <hip/hip_runtime.h>

#define N_NODES 50000
#define N_EDGES 1600000
#define IN_F    256
#define OUT_F   128
#define N_REL   500
#define NEG_SLOPE 0.2f
#define EPS_F   1e-10f
#define NCHUNK  196   // ceil(50000/256)

// ---------------- GEMM: Wh = h @ W  (fp32) ------------
// 32 rows x 128 cols per block of 256 threads; K tiled by 64.
__global__ __launch_bounds__(256) void gemm_wh(
    const float* __restrict__ h,   // [N_NODES][IN_F]
    const float* __restrict__ W,   // [IN_F][OUT_F]
    float* __restrict__ Wh)        // [N_NODES][OUT_F]
{
    __shared__ float Wsh[64][128];  // 32 KB
    __shared__ float Hsh[32][64];   // 8 KB
    const int t  = threadIdx.x;
    const int r0 = blockIdx.x * 32;
    const int cg = t & 31;   // cols 4*cg .. 4*cg+3
    const int rg = t >> 5;   // rows 4*rg .. 4*rg+3
    float acc[4][4] = {};

    for (int k0 = 0; k0 < IN_F; k0 += 64) {
        // stage W tile 64x128 (2048 float4, 8 per thread)
        #pragma unroll
        for (int i = 0; i < 8; ++i) {
            int q   = t + 256 * i;
            int row = q >> 5;
            int c4  = (q & 31) * 4;
            *(float4*)(&Wsh[row][c4]) = *(const float4*)(W + (k0 + row) * OUT_F + c4);
        }
        // stage H tile 32x64 (512 float4, 2 per thread)
        #pragma unroll
        for (int i = 0; i < 2; ++i) {
            int q   = t + 256 * i;
            int row = q >> 4;
            int c4  = (q & 15) * 4;
            int gr  = r0 + row;
            float4 v = make_float4(0.f, 0.f, 0.f, 0.f);
            if (gr < N_NODES) v = *(const float4*)(h + gr * IN_F + k0 + c4);
            *(float4*)(&Hsh[row][c4]) = v;
        }
        __syncthreads();

        #pragma unroll 2
        for (int k = 0; k < 64; k += 4) {
            float A[4][4];
            #pragma unroll
            for (int r = 0; r < 4; ++r)
                *(float4*)(A[r]) = *(const float4*)(&Hsh[4 * rg + r][k]);
            #pragma unroll
            for (int kk = 0; kk < 4; ++kk) {
                float4 b = *(const float4*)(&Wsh[k + kk][4 * cg]);
                #pragma unroll
                for (int r = 0; r < 4; ++r) {
                    acc[r][0] += A[r][kk] * b.x;
                    acc[r][1] += A[r][kk] * b.y;
                    acc[r][2] += A[r][kk] * b.z;
                    acc[r][3] += A[r][kk] * b.w;
                }
            }
        }
        __syncthreads();
    }
    #pragma unroll
    for (int r = 0; r < 4; ++r) {
        int gr = r0 + 4 * rg + r;
        if (gr < N_NODES) {
            float4 v = make_float4(acc[r][0], acc[r][1], acc[r][2], acc[r][3]);
            *(float4*)(Wh + gr * OUT_F + 4 * cg) = v;
        }
    }
}

// ------------- per-node s_i, s_j and per-relation s_rel (wave per item) ------
__global__ __launch_bounds__(256) void s_kernel(
    const float* __restrict__ Wh,
    const float* __restrict__ rel_emb,
    const float* __restrict__ a,     // [384]
    float* __restrict__ s_i, float* __restrict__ s_j, float* __restrict__ s_rel)
{
    int wid  = blockIdx.x * 4 + (threadIdx.x >> 6);
    int lane = threadIdx.x & 63;
    if (wid < N_NODES) {
        float2 v  = *(const float2*)(Wh + (size_t)wid * OUT_F + 2 * lane);
        float2 ai = *(const float2*)(a + 2 * lane);
        float2 aj = *(const float2*)(a + OUT_F + 2 * lane);
        float si = v.x * ai.x + v.y * ai.y;
        float sj = v.x * aj.x + v.y * aj.y;
        #pragma unroll
        for (int off = 32; off; off >>= 1) {
            si += __shfl_xor(si, off, 64);
            sj += __shfl_xor(sj, off, 64);
        }
        if (lane == 0) { s_i[wid] = si; s_j[wid] = sj; }
    } else {
        int rid = wid - N_NODES;
        if (rid < N_REL) {
            float2 re = *(const float2*)(rel_emb + (size_t)rid * OUT_F + 2 * lane);
            float2 ar = *(const float2*)(a + 2 * OUT_F + 2 * lane);
            float sr = re.x * ar.x + re.y * ar.y;
            #pragma unroll
            for (int off = 32; off; off >>= 1) sr += __shfl_xor(sr, off, 64);
            if (lane == 0) s_rel[rid] = sr;
        }
    }
}

// ---------------- CSR build ----------------
__global__ __launch_bounds__(256) void count_k(const int* __restrict__ rows, int* __restrict__ cnt) {
    int e = blockIdx.x * 256 + threadIdx.x;
    if (e < N_EDGES) atomicAdd(&cnt[rows[e]], 1);
}

__global__ __launch_bounds__(256) void scan_a(const int* __restrict__ cnt,
                                              int* __restrict__ row_start,
                                              int* __restrict__ partials)
{
    __shared__ int sh[256];
    int idx = blockIdx.x * 256 + threadIdx.x;
    int v = (idx < N_NODES) ? cnt[idx] : 0;
    sh[threadIdx.x] = v;
    __syncthreads();
    for (int off = 1; off < 256; off <<= 1) {
        int t2 = (threadIdx.x >= off) ? sh[threadIdx.x - off] : 0;
        __syncthreads();
        sh[threadIdx.x] += t2;
        __syncthreads();
    }
    if (idx < N_NODES) row_start[idx + 1] = sh[threadIdx.x];
    if (threadIdx.x == 255) partials[blockIdx.x] = sh[255];
}

__global__ __launch_bounds__(256) void scan_b(const int* __restrict__ partials,
                                              int* __restrict__ chunk_off)
{
    __shared__ int sh[256];
    int t = threadIdx.x;
    int v = (t < NCHUNK) ? partials[t] : 0;
    sh[t] = v;
    __syncthreads();
    for (int off = 1; off < 256; off <<= 1) {
        int t2 = (t >= off) ? sh[t - off] : 0;
        __syncthreads();
        sh[t] += t2;
        __syncthreads();
    }
    if (t < NCHUNK) chunk_off[t] = sh[t] - v;   // exclusive
}

__global__ __launch_bounds__(256) void scan_c(int* __restrict__ row_start,
                                              const int* __restrict__ chunk_off)
{
    int idx = blockIdx.x * 256 + threadIdx.x;
    if (idx < N_NODES) row_start[idx + 1] += chunk_off[blockIdx.x];
    if (idx == 0) row_start[0] = 0;
}

// ------------- per-edge weight + CSR scatter -------------
__global__ __launch_bounds__(256) void scatter_k(
    const int* __restrict__ rows, const int* __restrict__ cols, const int* __restrict__ types,
    const float* __restrict__ s_i, const float* __restrict__ s_j, const float* __restrict__ s_rel,
    int* __restrict__ next, float* __restrict__ edge_w, int* __restrict__ edge_col)
{
    int e = blockIdx.x * 256 + threadIdx.x;
    if (e >= N_EDGES) return;
    int r = rows[e], c = cols[e], t = types[e];
    float v = s_i[r] + s_j[c] + s_rel[t];
    v = (v > 0.f) ? v : NEG_SLOPE * v;      // leaky relu
    float w = __expf(v);                     // global-max shift cancels to ~1e-10 rel
    int pos = atomicAdd(&next[r], 1);
    edge_w[pos]   = w;
    edge_col[pos] = c;
}

// ------------- row aggregation: wave per row, no atomics -------------
__global__ __launch_bounds__(256) void aggregate_k(
    const int* __restrict__ row_start, const float* __restrict__ edge_w,
    const int* __restrict__ edge_col, const float* __restrict__ Wh,
    float* __restrict__ out)
{
    int r = blockIdx.x * 4 + (threadIdx.x >> 6);
    if (r >= N_NODES) return;
    int lane  = threadIdx.x & 63;
    int start = row_start[r], end = row_start[r + 1];

    float s = 0.f;
    for (int i = start + lane; i < end; i += 64) s += edge_w[i];
    #pragma unroll
    for (int off = 32; off; off >>= 1) s += __shfl_xor(s, off, 64);
    float inv = 1.f / (s + EPS_F);

    float a0 = 0.f, a1 = 0.f;
    for (int i = start; i < end; ++i) {
        float al = edge_w[i] * inv;
        int   c  = edge_col[i];
        float2 v = *(const float2*)(Wh + (size_t)c * OUT_F + 2 * lane);
        a0 += al * v.x;
        a1 += al * v.y;
    }
    float o0 = (a0 > 0.f) ? a0 : (__expf(a0) - 1.f);  // elu
    float o1 = (a1 > 0.f) ? a1 : (__expf(a1) - 1.f);
    *(float2*)(out + (size_t)r * OUT_F + 2 * lane) = make_float2(o0, o1);
}

// ---------------------------------------------------------------------------
extern "C" void kernel_launch(void* const* d_in, const int* in_sizes, int n_in,
                              void* d_out, int out_size, void* d_ws, size_t ws_size,
                              hipStream_t stream)
{
    const float* h     = (const float*)d_in[0];
    const int*   rows  = (const int*)d_in[1];
    const int*   cols  = (const int*)d_in[2];
    const int*   types = (const int*)d_in[3];
    const float* W     = (const float*)d_in[4];
    const float* rel   = (const float*)d_in[5];
    const float* a     = (const float*)d_in[6];

    char* ws = (char*)d_ws;
    size_t off = 0;
    auto alloc = [&](size_t bytes) -> void* {
        void* p = ws + off;
        off = (off + bytes + 255) & ~(size_t)255;
        return p;
    };
    float* Wh        = (float*)alloc((size_t)N_NODES * OUT_F * 4);
    float* s_i       = (float*)alloc((size_t)N_NODES * 4);
    float* s_j       = (float*)alloc((size_t)N_NODES * 4);
    float* s_rel     = (float*)alloc((size_t)N_REL * 4);
    int*   cnt       = (int*)alloc((size_t)N_NODES * 4);
    int*   row_start = (int*)alloc((size_t)(N_NODES + 1) * 4);
    int*   chunk_par = (int*)alloc((size_t)NCHUNK * 4);
    int*   chunk_off = (int*)alloc((size_t)NCHUNK * 4);
    int*   next      = (int*)alloc((size_t)N_NODES * 4);
    float* edge_w    = (float*)alloc((size_t)N_EDGES * 4);
    int*   edge_col  = (int*)alloc((size_t)N_EDGES * 4);
    (void)ws_size; (void)in_sizes; (void)n_in; (void)out_size;

    hipMemsetAsync(cnt, 0, (size_t)N_NODES * 4, stream);

    gemm_wh<<<(N_NODES + 31) / 32, 256, 0, stream>>>(h, W, Wh);
    s_kernel<<<(N_NODES + N_REL + 3) / 4, 256, 0, stream>>>(Wh, rel, a, s_i, s_j, s_rel);
    count_k<<<(N_EDGES + 255) / 256, 256, 0, stream>>>(rows, cnt);
    scan_a<<<NCHUNK, 256, 0, stream>>>(cnt, row_start, chunk_par);
    scan_b<<<1, 256, 0, stream>>>(chunk_par, chunk_off);
    scan_c<<<NCHUNK, 256, 0, stream>>>(row_start, chunk_off);
    hipMemcpyAsync(next, row_start, (size_t)N_NODES * 4, hipMemcpyDeviceToDevice, stream);
    scatter_k<<<(N_EDGES + 255) / 256, 256, 0, stream>>>(rows, cols, types,
                                                         s_i, s_j, s_rel,
                                                         next, edge_w, edge_col);
    aggregate_k<<<(N_NODES + 3) / 4, 256, 0, stream>>>(row_start, edge_w, edge_col, Wh,
                                                       (float*)d_out);
}

// Round 3
// 350.658 us; speedup vs baseline: 1.4281x; 1.4281x over previous
//
#include <hip/hip_runtime.h>

#define N_NODES 50000
#define N_EDGES 1600000
#define IN_F    256
#define OUT_F   128
#define N_REL   500
#define NEG_SLOPE 0.2f
#define EPS_F   1e-10f
#define NCHUNK  196   // ceil(50000/256)
#define GEMM_ROWS 64  // rows per gemm block

typedef __attribute__((ext_vector_type(8))) __bf16 bf16x8;
typedef __attribute__((ext_vector_type(8))) short short8;
typedef __attribute__((ext_vector_type(4))) float f32x4;

static __device__ __forceinline__ float bf2f(unsigned short u) {
    unsigned v = ((unsigned)u) << 16;
    float f;
    __builtin_memcpy(&f, &v, 4);
    return f;
}
static __device__ __forceinline__ unsigned short f2bf(float f) {
    unsigned u;
    __builtin_memcpy(&u, &f, 4);
    unsigned rounding = 0x7fffu + ((u >> 16) & 1u);
    u += rounding;
    return (unsigned short)(u >> 16);
}

// ---------------- GEMM: Whb = bf16(h @ W) via MFMA ------------
// Block = 256 thr (4 waves), 64 rows. Wave wv owns cols [32wv, 32wv+32).
// A (h rows, bf16) staged in LDS in MFMA-fragment order; B (W) in registers.
// mfma_f32_16x16x32_bf16: A[m=lane&15][k=quad*8+j], B[k=quad*8+j][n=lane&15],
// D col=lane&15, row=quad*4+reg  (HW-verified layouts per guide §3/m120).
__global__ __launch_bounds__(256) void gemm_wh(
    const float* __restrict__ h,   // [N_NODES][IN_F] fp32
    const float* __restrict__ W,   // [IN_F][OUT_F]  fp32
    unsigned short* __restrict__ Whb)  // [N_NODES][OUT_F] bf16
{
    __shared__ unsigned short Ash[GEMM_ROWS * IN_F];  // 32 KB, fragment order
    const int t    = threadIdx.x;
    const int wv   = t >> 6;
    const int lane = t & 63;
    const int quad = lane >> 4;
    const int l15  = lane & 15;
    const int r0   = blockIdx.x * GEMM_ROWS;

    // ---- B fragments: W cols for this wave, bf16, in registers ----
    bf16x8 Bfrag[2][8];
    #pragma unroll
    for (int ct2 = 0; ct2 < 2; ++ct2) {
        int n = 32 * wv + 16 * ct2 + l15;
        #pragma unroll
        for (int ks = 0; ks < 8; ++ks) {
            short8 tmp;
            #pragma unroll
            for (int j = 0; j < 8; ++j) {
                int k = 32 * ks + 8 * quad + j;
                tmp[j] = (short)f2bf(W[k * OUT_F + n]);
            }
            Bfrag[ct2][ks] = __builtin_bit_cast(bf16x8, tmp);
        }
    }

    // ---- stage A (64 rows x 256 k) into LDS in fragment order ----
    // element (row,k) -> Ash[ ((rg*8+ks)*64 + (qd<<4|m15)) * 8 + j ]
    #pragma unroll
    for (int i = 0; i < 16; ++i) {
        int q   = t + 256 * i;        // 0..4095 float4-groups
        int row = q >> 6;             // 0..63
        int k   = (q & 63) * 4;       // k, k+1, k+2, k+3
        int gr  = r0 + row;
        float4 v = make_float4(0.f, 0.f, 0.f, 0.f);
        if (gr < N_NODES) v = *(const float4*)(h + (size_t)gr * IN_F + k);
        int ks = k >> 5, qd = (k >> 3) & 3, j = k & 7;   // j in {0,4}
        int rg = row >> 4, m15 = row & 15;
        int off = ((((rg << 3) + ks) << 6) + ((qd << 4) | m15)) * 8 + j;
        ushort4 p;
        p.x = f2bf(v.x); p.y = f2bf(v.y); p.z = f2bf(v.z); p.w = f2bf(v.w);
        *(ushort4*)(Ash + off) = p;
    }
    __syncthreads();

    // ---- MFMA main loop: 4 row-groups x 8 ksteps x 2 ctiles ----
    #pragma unroll 1
    for (int rg = 0; rg < 4; ++rg) {
        const unsigned short* base = Ash + (((rg << 3) << 6) + lane) * 8;
        bf16x8 Afrag[8];
        #pragma unroll
        for (int ks = 0; ks < 8; ++ks)
            Afrag[ks] = *(const bf16x8*)(base + (ks << 6) * 8);
        f32x4 acc0 = {0.f, 0.f, 0.f, 0.f};
        f32x4 acc1 = {0.f, 0.f, 0.f, 0.f};
        #pragma unroll
        for (int ks = 0; ks < 8; ++ks) {
            acc0 = __builtin_amdgcn_mfma_f32_16x16x32_bf16(Afrag[ks], Bfrag[0][ks], acc0, 0, 0, 0);
            acc1 = __builtin_amdgcn_mfma_f32_16x16x32_bf16(Afrag[ks], Bfrag[1][ks], acc1, 0, 0, 0);
        }
        // epilogue: D col=lane&15 (global 32wv+16ct2+l15), row=quad*4+reg
        #pragma unroll
        for (int reg = 0; reg < 4; ++reg) {
            int gr = r0 + 16 * rg + quad * 4 + reg;
            if (gr < N_NODES) {
                Whb[(size_t)gr * OUT_F + 32 * wv + l15]      = f2bf(acc0[reg]);
                Whb[(size_t)gr * OUT_F + 32 * wv + 16 + l15] = f2bf(acc1[reg]);
            }
        }
    }
}

// ------------- per-node s_i, s_j (bf16 Wh) and per-relation s_rel ------------
__global__ __launch_bounds__(256) void s_kernel(
    const unsigned short* __restrict__ Whb,
    const float* __restrict__ rel_emb,
    const float* __restrict__ a,     // [384] fp32
    float* __restrict__ s_i, float* __restrict__ s_j, float* __restrict__ s_rel)
{
    int wid  = blockIdx.x * 4 + (threadIdx.x >> 6);
    int lane = threadIdx.x & 63;
    if (wid < N_NODES) {
        unsigned pk = ((const unsigned*)Whb)[(size_t)wid * 64 + lane];
        float v0 = bf2f(pk & 0xffffu), v1 = bf2f(pk >> 16);
        float2 ai = *(const float2*)(a + 2 * lane);
        float2 aj = *(const float2*)(a + OUT_F + 2 * lane);
        float si = v0 * ai.x + v1 * ai.y;
        float sj = v0 * aj.x + v1 * aj.y;
        #pragma unroll
        for (int off = 32; off; off >>= 1) {
            si += __shfl_xor(si, off, 64);
            sj += __shfl_xor(sj, off, 64);
        }
        if (lane == 0) { s_i[wid] = si; s_j[wid] = sj; }
    } else {
        int rid = wid - N_NODES;
        if (rid < N_REL) {
            float2 re = *(const float2*)(rel_emb + (size_t)rid * OUT_F + 2 * lane);
            float2 ar = *(const float2*)(a + 2 * OUT_F + 2 * lane);
            float sr = re.x * ar.x + re.y * ar.y;
            #pragma unroll
            for (int off = 32; off; off >>= 1) sr += __shfl_xor(sr, off, 64);
            if (lane == 0) s_rel[rid] = sr;
        }
    }
}

// ---------------- CSR build ----------------
__global__ __launch_bounds__(256) void count_k(const int* __restrict__ rows, int* __restrict__ cnt) {
    int e = blockIdx.x * 256 + threadIdx.x;
    if (e < N_EDGES) atomicAdd(&cnt[rows[e]], 1);
}

__global__ __launch_bounds__(256) void scan_a(const int* __restrict__ cnt,
                                              int* __restrict__ row_start,
                                              int* __restrict__ partials)
{
    __shared__ int sh[256];
    int idx = blockIdx.x * 256 + threadIdx.x;
    int v = (idx < N_NODES) ? cnt[idx] : 0;
    sh[threadIdx.x] = v;
    __syncthreads();
    for (int off = 1; off < 256; off <<= 1) {
        int t2 = (threadIdx.x >= off) ? sh[threadIdx.x - off] : 0;
        __syncthreads();
        sh[threadIdx.x] += t2;
        __syncthreads();
    }
    if (idx < N_NODES) row_start[idx + 1] = sh[threadIdx.x];
    if (threadIdx.x == 255) partials[blockIdx.x] = sh[255];
}

__global__ __launch_bounds__(256) void scan_b(const int* __restrict__ partials,
                                              int* __restrict__ chunk_off)
{
    __shared__ int sh[256];
    int t = threadIdx.x;
    int v = (t < NCHUNK) ? partials[t] : 0;
    sh[t] = v;
    __syncthreads();
    for (int off = 1; off < 256; off <<= 1) {
        int t2 = (t >= off) ? sh[t - off] : 0;
        __syncthreads();
        sh[t] += t2;
        __syncthreads();
    }
    if (t < NCHUNK) chunk_off[t] = sh[t] - v;   // exclusive
}

__global__ __launch_bounds__(256) void scan_c(int* __restrict__ row_start,
                                              const int* __restrict__ chunk_off)
{
    int idx = blockIdx.x * 256 + threadIdx.x;
    if (idx < N_NODES) row_start[idx + 1] += chunk_off[blockIdx.x];
    if (idx == 0) row_start[0] = 0;
}

// ------------- per-edge weight + CSR scatter (packed 8B) -------------
__global__ __launch_bounds__(256) void scatter_k(
    const int* __restrict__ rows, const int* __restrict__ cols, const int* __restrict__ types,
    const float* __restrict__ s_i, const float* __restrict__ s_j, const float* __restrict__ s_rel,
    int* __restrict__ next, uint2* __restrict__ epk)
{
    int e = blockIdx.x * 256 + threadIdx.x;
    if (e >= N_EDGES) return;
    int r = rows[e], c = cols[e], t = types[e];
    float v = s_i[r] + s_j[c] + s_rel[t];
    v = (v > 0.f) ? v : NEG_SLOPE * v;      // leaky relu
    float w = __expf(v);                     // global-max shift cancels to ~1e-10 rel
    int pos = atomicAdd(&next[r], 1);
    epk[pos] = make_uint2(__float_as_uint(w), (unsigned)c);
}

// ------------- row aggregation: wave per row, single pass, unroll-4 ---------
__global__ __launch_bounds__(256) void aggregate_k(
    const int* __restrict__ row_start, const uint2* __restrict__ epk,
    const unsigned short* __restrict__ Whb,
    float* __restrict__ out)
{
    int r = blockIdx.x * 4 + (threadIdx.x >> 6);
    if (r >= N_NODES) return;
    int lane  = threadIdx.x & 63;
    int start = row_start[r], end = row_start[r + 1];
    const unsigned* Whu = (const unsigned*)Whb;

    float s = 0.f, a0 = 0.f, a1 = 0.f;
    int i = start;
    for (; i + 4 <= end; i += 4) {
        uint2 e0 = epk[i], e1 = epk[i + 1], e2 = epk[i + 2], e3 = epk[i + 3];
        unsigned p0 = Whu[(size_t)e0.y * 64 + lane];
        unsigned p1 = Whu[(size_t)e1.y * 64 + lane];
        unsigned p2 = Whu[(size_t)e2.y * 64 + lane];
        unsigned p3 = Whu[(size_t)e3.y * 64 + lane];
        float w0 = __uint_as_float(e0.x), w1 = __uint_as_float(e1.x);
        float w2 = __uint_as_float(e2.x), w3 = __uint_as_float(e3.x);
        s  += (w0 + w1) + (w2 + w3);
        a0 += w0 * bf2f(p0 & 0xffffu) + w1 * bf2f(p1 & 0xffffu)
            + w2 * bf2f(p2 & 0xffffu) + w3 * bf2f(p3 & 0xffffu);
        a1 += w0 * bf2f(p0 >> 16) + w1 * bf2f(p1 >> 16)
            + w2 * bf2f(p2 >> 16) + w3 * bf2f(p3 >> 16);
    }
    for (; i < end; ++i) {
        uint2 e0 = epk[i];
        unsigned p0 = Whu[(size_t)e0.y * 64 + lane];
        float w0 = __uint_as_float(e0.x);
        s  += w0;
        a0 += w0 * bf2f(p0 & 0xffffu);
        a1 += w0 * bf2f(p0 >> 16);
    }
    float inv = 1.f / (s + EPS_F);
    a0 *= inv; a1 *= inv;
    float o0 = (a0 > 0.f) ? a0 : (__expf(a0) - 1.f);  // elu
    float o1 = (a1 > 0.f) ? a1 : (__expf(a1) - 1.f);
    *(float2*)(out + (size_t)r * OUT_F + 2 * lane) = make_float2(o0, o1);
}

// ---------------------------------------------------------------------------
extern "C" void kernel_launch(void* const* d_in, const int* in_sizes, int n_in,
                              void* d_out, int out_size, void* d_ws, size_t ws_size,
                              hipStream_t stream)
{
    const float* h     = (const float*)d_in[0];
    const int*   rows  = (const int*)d_in[1];
    const int*   cols  = (const int*)d_in[2];
    const int*   types = (const int*)d_in[3];
    const float* W     = (const float*)d_in[4];
    const float* rel   = (const float*)d_in[5];
    const float* a     = (const float*)d_in[6];

    char* ws = (char*)d_ws;
    size_t off = 0;
    auto alloc = [&](size_t bytes) -> void* {
        void* p = ws + off;
        off = (off + bytes + 255) & ~(size_t)255;
        return p;
    };
    unsigned short* Whb = (unsigned short*)alloc((size_t)N_NODES * OUT_F * 2);
    float* s_i       = (float*)alloc((size_t)N_NODES * 4);
    float* s_j       = (float*)alloc((size_t)N_NODES * 4);
    float* s_rel     = (float*)alloc((size_t)N_REL * 4);
    int*   cnt       = (int*)alloc((size_t)N_NODES * 4);
    int*   row_start = (int*)alloc((size_t)(N_NODES + 1) * 4);
    int*   chunk_par = (int*)alloc((size_t)NCHUNK * 4);
    int*   chunk_off = (int*)alloc((size_t)NCHUNK * 4);
    int*   next      = (int*)alloc((size_t)N_NODES * 4);
    uint2* epk       = (uint2*)alloc((size_t)N_EDGES * 8);
    (void)ws_size; (void)in_sizes; (void)n_in; (void)out_size;

    hipMemsetAsync(cnt, 0, (size_t)N_NODES * 4, stream);

    gemm_wh<<<(N_NODES + GEMM_ROWS - 1) / GEMM_ROWS, 256, 0, stream>>>(h, W, Whb);
    s_kernel<<<(N_NODES + N_REL + 3) / 4, 256, 0, stream>>>(Whb, rel, a, s_i, s_j, s_rel);
    count_k<<<(N_EDGES + 255) / 256, 256, 0, stream>>>(rows, cnt);
    scan_a<<<NCHUNK, 256, 0, stream>>>(cnt, row_start, chunk_par);
    scan_b<<<1, 256, 0, stream>>>(chunk_par, chunk_off);
    scan_c<<<NCHUNK, 256, 0, stream>>>(row_start, chunk_off);
    hipMemcpyAsync(next, row_start, (size_t)N_NODES * 4, hipMemcpyDeviceToDevice, stream);
    scatter_k<<<(N_EDGES + 255) / 256, 256, 0, stream>>>(rows, cols, types,
                                                         s_i, s_j, s_rel, next, epk);
    aggregate_k<<<(N_NODES + 3) / 4, 256, 0, stream>>>(row_start, epk, Whb, (float*)d_out);
}